// Round 3
// 411.939 us; speedup vs baseline: 1.0214x; 1.0214x over previous
//
#include <hip/hip_runtime.h>

#define TT   1024
#define NW   34          // 32-step windows; slope-1 skew offset up to 63
#define NPH  (NW + 9)    // barrier pipeline phases: NW + 3*(4 waves - 1)
#define FINF 1e30f

template<bool A> struct BoolC { static constexpr bool value = A; };

// dirs layout (bit format as earlier rounds, keyed by 64-row band):
//   uint2 {ne2_mask, diag_mask} at ((b*16+bi)*NW + T)*64 + rr
//   bit k of window T = col 32T - o + k, o = skew lane of row rr:
//   o = (bi&3)*16 + (rr>>2)  [4 waves x 256 rows, 4 rows/lane, slope-1]
// ne2: dir != left. diag: dir == diag (first-min argmin).

// DPP wave_shr:1 == __shfl_up(x,1) but pure-VALU (no ds_bpermute / lgkm wait).
// Lane 0 result is old(=0) with bound_ctrl off; lane 0's u is overridden anyway.
__device__ __forceinline__ float dpp_wave_shr1(float x) {
    return __int_as_float(__builtin_amdgcn_update_dpp(
        0, __float_as_int(x), 0x138, 0xF, 0xF, false));
}

// ---------------- K1: forward DP, 1 batch/block, 4 waves, barrier pipeline --
// Wave w owns rows 256w..256w+255; lane L owns rows 256w+4L..+4L+3. Slope-1
// skew: at step s lane L computes col s-L for its 4 rows (chain = DPP shift +
// 4 chained cells). Inter-wave handoff via LDS mailbox rows, made safe by
// DETERMINISTIC barrier pipelining: wave w runs window T = G - 3w at phase G
// (producer is provably >= 2 complete windows ahead; no spin, no atomics).
// cur starts FINF for ALL lanes; (0,0) via the best>9e29 clamp (ACT peel T<2).
__global__ __launch_bounds__(256) void dtw_forward(
    const float* __restrict__ preds,
    const float* __restrict__ targs,
    uint2* __restrict__ dirs)
{
    __shared__ float2 qsh[TT];
    __shared__ float  mbox[3][TT];

    const int tid  = threadIdx.x;
    const int w    = tid >> 6;
    const int lane = tid & 63;
    const int b    = blockIdx.x;

    for (int k = tid; k < TT; k += 256) {
        float4 t4 = ((const float4*)targs)[(size_t)b * TT + k];
        qsh[k] = make_float2(t4.x, t4.y);
    }
    for (int k = tid; k < 3 * TT; k += 256) ((float*)mbox)[k] = FINF;

    float px[4], py[4];
    {
        const int row0 = w * 256 + 4 * lane;
#pragma unroll
        for (int r = 0; r < 4; ++r) {
            float4 pv = ((const float4*)preds)[(size_t)b * TT + row0 + r];
            px[r] = pv.x; py[r] = pv.y;
        }
    }
    __syncthreads();

    const float* src = (w > 0) ? mbox[w - 1] : nullptr;
    float*       dst = (w < 3) ? mbox[w]     : nullptr;

    float cur0 = FINF, cur1 = FINF, cur2 = FINF, cur3 = FINF;
    float uprev = FINF, shp = FINF;
    unsigned au0 = 0, ad0 = 0, au1 = 0, ad1 = 0;
    unsigned au2 = 0, ad2 = 0, au3 = 0, ad3 = 0;
    float bnd[8];
#pragma unroll
    for (int k = 0; k < 8; ++k) bnd[k] = FINF;

    const int bi  = 4 * w + (lane >> 4);     // 64-row band index (within batch)
    const int rr0 = 4 * (lane & 15);         // row within band
    const bool is63 = (lane == 63);

    for (int G = 0; G < NPH; ++G) {
        const int T = G - 3 * w;             // wave-uniform window index
        if ((unsigned)T < (unsigned)NW) {
            auto body = [&](auto actc) {
                constexpr bool ACT = decltype(actc)::value;
#pragma unroll 1
                for (int sub = 0; sub < 4; ++sub) {
                    const int s0 = 32 * T + 8 * sub;
                    // q for this 8-group: LDS -> regs (conflict-free, off-chain)
                    float qx[8], qy[8];
#pragma unroll
                    for (int k2 = 0; k2 < 8; ++k2) {
                        float2 qv = qsh[(s0 + k2 - lane) & (TT - 1)];
                        qx[k2] = qv.x; qy[k2] = qv.y;
                    }
                    // boundary cols from producer wave (ordered by phase barrier)
                    if (w > 0 && s0 < TT) {
#pragma unroll
                        for (int k2 = 0; k2 < 8; ++k2) bnd[k2] = src[s0 + k2];
                    }
                    float bq[8];
#pragma unroll
                    for (int k2 = 0; k2 < 8; ++k2) {
                        const int s = s0 + k2;
                        float d[4];
#pragma unroll
                        for (int r = 0; r < 4; ++r) {
                            const float dx = px[r] - qx[k2];
                            const float dy = py[r] - qy[k2];
                            d[r] = __builtin_amdgcn_sqrtf(dx * dx + dy * dy);
                        }

                        const float u = (lane == 0) ? ((w == 0) ? FINF : bnd[k2]) : shp;
                        const float c0o = cur0, c1o = cur1, c2o = cur2, c3o = cur3;

                        // row0: cd=uprev, cu=u, cl=c0o (clamp fires only at (0,0))
                        float m2a = fminf(u, c0o);
                        float ba  = fminf(uprev, m2a);
                        if constexpr (ACT) ba = (ba > 9e29f) ? 0.0f : ba;
                        const float v0 = d[0] + ba;
                        const unsigned bd0 = (uprev <= m2a) ? 1u : 0u;
                        const unsigned bu0 = ((u <= c0o) ? 1u : 0u) | bd0;
                        // row1: cd=c0o, cu=v0, cl=c1o
                        float m2b = fminf(v0, c1o);
                        const float v1 = d[1] + fminf(c0o, m2b);
                        const unsigned bd1 = (c0o <= m2b) ? 1u : 0u;
                        const unsigned bu1 = ((v0 <= c1o) ? 1u : 0u) | bd1;
                        // row2: cd=c1o, cu=v1, cl=c2o
                        float m2c = fminf(v1, c2o);
                        const float v2 = d[2] + fminf(c1o, m2c);
                        const unsigned bd2 = (c1o <= m2c) ? 1u : 0u;
                        const unsigned bu2 = ((v1 <= c2o) ? 1u : 0u) | bd2;
                        // row3: cd=c2o, cu=v2, cl=c3o
                        float m2d = fminf(v2, c3o);
                        const float v3 = d[3] + fminf(c2o, m2d);
                        const unsigned bd3 = (c2o <= m2d) ? 1u : 0u;
                        const unsigned bu3 = ((v2 <= c3o) ? 1u : 0u) | bd3;

                        au0 = (au0 << 1) | bu0;  ad0 = (ad0 << 1) | bd0;
                        au1 = (au1 << 1) | bu1;  ad1 = (ad1 << 1) | bd1;
                        au2 = (au2 << 1) | bu2;  ad2 = (ad2 << 1) | bd2;
                        au3 = (au3 << 1) | bu3;  ad3 = (ad3 << 1) | bd3;

                        if constexpr (ACT) {
                            const bool act = (lane <= s);
                            cur0 = act ? v0 : c0o;
                            cur1 = act ? v1 : c1o;
                            cur2 = act ? v2 : c2o;
                            cur3 = act ? v3 : c3o;
                        } else {
                            cur0 = v0; cur1 = v1; cur2 = v2; cur3 = v3;
                        }
                        uprev = u;
                        bq[k2] = cur3;
                        shp = dpp_wave_shr1(cur3);   // for next step (col s+1-L)
                    }
                    // batched boundary publish (plain LDS; barrier orders it)
                    if (is63 && w < 3) {
#pragma unroll
                        for (int k2 = 0; k2 < 8; ++k2) {
                            const int c = s0 + k2 - 63;
                            if ((unsigned)c < 1024u) dst[c] = bq[k2];
                        }
                    }
                }
            };
            if (T < 2) body(BoolC<true>{}); else body(BoolC<false>{});

            const size_t base = (size_t)((b * 16 + bi) * NW + T) * 64 + rr0;
            uint4* dp = (uint4*)&dirs[base];
            dp[0] = make_uint4(__builtin_bitreverse32(au0), __builtin_bitreverse32(ad0),
                               __builtin_bitreverse32(au1), __builtin_bitreverse32(ad1));
            dp[1] = make_uint4(__builtin_bitreverse32(au2), __builtin_bitreverse32(ad2),
                               __builtin_bitreverse32(au3), __builtin_bitreverse32(ad3));
            au0 = ad0 = au1 = ad1 = au2 = ad2 = au3 = ad3 = 0u;
        }
        __syncthreads();   // phase barrier (uniform across the block)
    }
}

// ---------------- K2: exit-only per-band walk (no loss) ----------------
__global__ __launch_bounds__(1024) void dtw_exits(
    const uint2* __restrict__ dirs,
    unsigned short* __restrict__ exitc)
{
    __shared__ uint2 raw[NW * 64];
    __shared__ unsigned nebit[64][32];
    __shared__ unsigned dgbit[64][32];

    const int tid = threadIdx.x;
    const int b = blockIdx.x >> 4, bi = blockIdx.x & 15;

    for (int i = tid; i < NW * 64; i += 1024)
        raw[i] = dirs[(size_t)(b * 16 + bi) * (NW * 64) + i];
    __syncthreads();
    for (int i = tid; i < 64 * 32; i += 1024) {
        const int rr = i >> 5, u = i & 31;
        const int o  = ((bi & 3) << 4) + (rr >> 2);   // slope-1, 4 rows/lane
        const int T0 = u + (o >> 5), sh = o & 31;
        uint2 A  = raw[T0 * 64 + rr];
        uint2 Bv = raw[(T0 + 1) * 64 + rr];
        nebit[rr][u] = sh ? ((A.x >> sh) | (Bv.x << (32 - sh))) : A.x;
        dgbit[rr][u] = sh ? ((A.y >> sh) | (Bv.y << (32 - sh))) : A.y;
    }
    __syncthreads();

    int j = tid;
    for (int rr = 63; rr >= 0; --rr) {
        if (bi == 0 && rr == 0) { j = 0; break; }
        int u = j >> 5, m = j & 31;
        unsigned wv = nebit[rr][u] << (31 - m);
        while (wv == 0u && u > 0) { --u; wv = nebit[rr][u]; m = 31; }
        const int j2 = (wv == 0u) ? 0 : ((u << 5) + m - __builtin_clz(wv));
        const int diag = (int)((dgbit[rr][j2 >> 5] >> (j2 & 31)) & 1u);
        j = j2 - diag;
        if (j < 0) j = 0;   // safety net (unreachable on correct dirs)
    }
    exitc[((size_t)(b * 16 + bi) << 10) + tid] = (unsigned short)j;
}

// ---------------- K3: stitch -> per-band entry columns ----------------
__global__ void dtw_entries(const unsigned short* __restrict__ exitc,
                            unsigned short* __restrict__ ent)
{
    const int b = threadIdx.x;
    int j = TT - 1;
    for (int bi = 15; bi >= 0; --bi) {
        ent[b * 16 + bi] = (unsigned short)j;
        j = exitc[((size_t)(b * 16 + bi) << 10) + j];
    }
}

// ---------------- K4: loss replay on the 16 true segments per batch --------
__global__ __launch_bounds__(64) void dtw_loss(
    const float* __restrict__ preds,
    const float* __restrict__ targs,
    const float* __restrict__ subcoef,
    const uint2* __restrict__ dirs,
    const unsigned short* __restrict__ ent,
    float* __restrict__ out)
{
    __shared__ uint2 raw[NW * 64];
    __shared__ unsigned nebit[64][32];
    __shared__ unsigned dgbit[64][32];
    __shared__ float2 qsh[TT];
    __shared__ float2 psh[64];
    __shared__ unsigned recs[160];

    const int lane = threadIdx.x;
    const int b = blockIdx.x >> 4, bi = blockIdx.x & 15;

    for (int i = lane; i < NW * 64; i += 64)
        raw[i] = dirs[(size_t)(b * 16 + bi) * (NW * 64) + i];
    for (int k = lane; k < TT; k += 64) {
        float4 t4 = ((const float4*)targs)[(size_t)b * TT + k];
        qsh[k] = make_float2(t4.x, t4.y);
    }
    {
        float4 p4 = ((const float4*)preds)[(size_t)b * TT + bi * 64 + lane];
        psh[lane] = make_float2(p4.x, p4.y);
    }
    __syncthreads();
    for (int i = lane; i < 64 * 32; i += 64) {
        const int rr = i >> 5, u = i & 31;
        const int o  = ((bi & 3) << 4) + (rr >> 2);   // slope-1, 4 rows/lane
        const int T0 = u + (o >> 5), sh = o & 31;
        uint2 A  = raw[T0 * 64 + rr];
        uint2 Bv = raw[(T0 + 1) * 64 + rr];
        nebit[rr][u] = sh ? ((A.x >> sh) | (Bv.x << (32 - sh))) : A.x;
        dgbit[rr][u] = sh ? ((A.y >> sh) | (Bv.y << (32 - sh))) : A.y;
    }
    __syncthreads();

    // wave-redundant replay; lane 0 records <=32-col span chunks
    int j = ent[b * 16 + bi];
    int nrec = 0;
    for (int rr = 63; rr >= 0; --rr) {
        int j2;
        if (bi == 0 && rr == 0) j2 = 0;
        else {
            int u = j >> 5, m = j & 31;
            unsigned wv = nebit[rr][u] << (31 - m);
            while (wv == 0u && u > 0) { --u; wv = nebit[rr][u]; m = 31; }
            j2 = (wv == 0u) ? 0 : ((u << 5) + m - __builtin_clz(wv));
        }
        int c = j;
        for (;;) {
            int cl = (c - 31 > j2) ? (c - 31) : j2;
            if (lane == 0)
                recs[nrec] = ((unsigned)rr << 20) | ((unsigned)cl << 10) | (unsigned)c;
            ++nrec;
            if (cl == j2) break;
            c = cl - 1;
        }
        if (bi == 0 && rr == 0) j = 0;
        else {
            const int diag = (int)((dgbit[rr][j2 >> 5] >> (j2 & 31)) & 1u);
            j = j2 - diag;
            if (j < 0) j = 0;   // safety net (unreachable on correct dirs)
        }
    }
    __syncthreads();

    const float sc0 = subcoef[0], sc1 = subcoef[1];
    float acc = 0.0f;
    for (int k = lane; k < nrec; k += 64) {
        unsigned rec = recs[k];
        int rr = (int)(rec >> 20), cl = (int)((rec >> 10) & 1023u), ch = (int)(rec & 1023u);
        float2 p = psh[rr];
        for (int c = cl; c <= ch; ++c) {
            float2 q = qsh[c];
            acc += fabsf(p.x - q.x) * sc0 + fabsf(p.y - q.y) * sc1;
        }
    }
    for (int o = 32; o; o >>= 1) acc += __shfl_down(acc, o);
    if (lane == 0) atomicAdd(out, acc);
}

extern "C" void kernel_launch(void* const* d_in, const int* in_sizes, int n_in,
                              void* d_out, int out_size, void* d_ws, size_t ws_size,
                              hipStream_t stream)
{
    const float* preds   = (const float*)d_in[0];
    const float* targs   = (const float*)d_in[1];
    const float* subcoef = (const float*)d_in[2];
    float* out = (float*)d_out;

    const int B = in_sizes[0] / (TT * 4);

    const size_t dirsBytes = (size_t)B * 16 * NW * 64 * sizeof(uint2);        // ~17.8 MB
    const size_t exitBytes = (size_t)B * 16 * 1024 * sizeof(unsigned short);  // 2 MB
    uint2* dirs = (uint2*)d_ws;
    unsigned short* exitc = (unsigned short*)((char*)d_ws + dirsBytes);
    unsigned short* ent   = (unsigned short*)((char*)d_ws + dirsBytes + exitBytes);

    hipMemsetAsync(out, 0, sizeof(float), stream);
    dtw_forward<<<dim3(B), dim3(256), 0, stream>>>(preds, targs, dirs);
    dtw_exits<<<dim3(B * 16), dim3(1024), 0, stream>>>(dirs, exitc);
    dtw_entries<<<dim3(1), dim3(B), 0, stream>>>(exitc, ent);
    dtw_loss<<<dim3(B * 16), dim3(64), 0, stream>>>(preds, targs, subcoef, dirs, ent, out);
}